// Round 4
// baseline (242.871 us; speedup 1.0000x reference)
//
#include <hip/hip_runtime.h>
#include <math.h>

#define D 1024
#define TOPK 32
#define VPT 16          // values per lane = D / 64
#define RPW 2           // rows per wave (ILP/MLP)
#define WAVES 4         // waves per block -> 256 threads

typedef float vfloat4 __attribute__((ext_vector_type(4)));

__device__ __forceinline__ void waveMax2(float& a, float& b) {
#pragma unroll
  for (int off = 32; off >= 1; off >>= 1) {
    a = fmaxf(a, __shfl_xor(a, off, 64));
    b = fmaxf(b, __shfl_xor(b, off, 64));
  }
}
__device__ __forceinline__ void waveSum2(float& a, float& b) {
#pragma unroll
  for (int off = 32; off >= 1; off >>= 1) {
    a += __shfl_xor(a, off, 64);
    b += __shfl_xor(b, off, 64);
  }
}

// tanh-approx GELU via one v_exp + one v_rcp. |err vs erf-GELU| ~3e-4.
__device__ __forceinline__ float fast_gelu(float x) {
  const float x2 = x * x;
  const float p = __builtin_fmaf(0.044715f, x2, 1.0f);
  const float a = -1.5957691216f * x * p;
  const float e = __expf(a);
  return x * __builtin_amdgcn_rcpf(1.0f + e);
}
// tanh(y) for y>=0: 1 - 2/(exp(2y)+1); exact at +inf (rcp(inf)=0).
__device__ __forceinline__ float fast_tanh_pos(float y) {
  const float e = __expf(2.0f * y);
  return 1.0f - 2.0f * __builtin_amdgcn_rcpf(e + 1.0f);
}

// Prep: per-channel rsqrt(clip(var)) -> ws[0..D-1]; exp(la),exp(ls) -> ws[D],ws[D+1]
__global__ __launch_bounds__(256) void prep_stats(const float* __restrict__ ema_mean,
                                                  const float* __restrict__ ema_sq,
                                                  const float* __restrict__ p_la,
                                                  const float* __restrict__ p_ls,
                                                  float* __restrict__ ws) {
  int i = blockIdx.x * 256 + threadIdx.x;
  if (i < D) {
    float m = ema_mean[i];
    float v = ema_sq[i] - m * m;
    ws[i] = rsqrtf(fmaxf(v, 1e-6f));
  }
  if (i == 0) {
    ws[D] = expf(p_la[0]);
    ws[D + 1] = expf(p_ls[0]);
  }
}

__global__ __launch_bounds__(256, 4) void gelu_gate(const float* __restrict__ x,
                                                    const float* __restrict__ ema_mean,
                                                    const float* __restrict__ ws,
                                                    float* __restrict__ out,
                                                    int n_rows) {
  const int wave = threadIdx.x >> 6;
  const int lane = threadIdx.x & 63;
  const int w = blockIdx.x * WAVES + wave;
  const int row0 = w * RPW;
  if (row0 >= n_rows) return;
  const bool has1 = (row0 + 1) < n_rows;
  const float* __restrict__ xr0 = x + (size_t)row0 * D;
  const float* __restrict__ xr1 = x + (size_t)(has1 ? row0 + 1 : row0) * D;

  // Load both rows (8 dwordx4 in flight), compute z-scores AND gelu eagerly.
  float za0[VPT], za1[VPT], g0[VPT], g1[VPT];
#pragma unroll
  for (int j = 0; j < 4; ++j) {
    const int c = j * 256 + lane * 4;
    const float4 a0 = *reinterpret_cast<const float4*>(xr0 + c);
    const float4 a1 = *reinterpret_cast<const float4*>(xr1 + c);
    const float4 mm = *reinterpret_cast<const float4*>(ema_mean + c);
    const float4 ss = *reinterpret_cast<const float4*>(ws + c);
    const float xs0[4] = {a0.x, a0.y, a0.z, a0.w};
    const float xs1[4] = {a1.x, a1.y, a1.z, a1.w};
    const float ms[4] = {mm.x, mm.y, mm.z, mm.w};
    const float is[4] = {ss.x, ss.y, ss.z, ss.w};
#pragma unroll
    for (int q = 0; q < 4; ++q) {
      const int i = 4 * j + q;
      za0[i] = fabsf(xs0[q] - ms[q]) * is[q];
      za1[i] = fabsf(xs1[q] - ms[q]) * is[q];
      g0[i] = fast_gelu(xs0[q]);
      g1[i] = fast_gelu(xs1[q]);
    }
  }

  // Row maxes (both rows reduced in lock-step for ILP).
  float m0 = 0.0f, m1 = 0.0f;
#pragma unroll
  for (int i = 0; i < VPT; ++i) {
    m0 = fmaxf(m0, za0[i]);
    m1 = fmaxf(m1, za1[i]);
  }
  waveMax2(m0, m1);

  // Dual exact bisection for the 32nd-largest of each row.
  // Invariants per row: count(za >= lo) >= TOPK, count(za >= hi) < TOPK.
  // Exit per row: count == TOPK (top-K set identified) or 1-ulp bracket.
  // All control state is wave-uniform (ballot counts land in SGPRs).
  float lo0 = 0.0f, hi0 = __uint_as_float(__float_as_uint(m0) + 1u);
  float lo1 = 0.0f, hi1 = __uint_as_float(__float_as_uint(m1) + 1u);
  bool done0 = false, done1 = !has1;
  while (!done0 || !done1) {
    float mid0 = 0.5f * (lo0 + hi0);
    float mid1 = 0.5f * (lo1 + hi1);
    if (!done0 && (!(mid0 > lo0) || !(mid0 < hi0))) done0 = true;
    if (!done1 && (!(mid1 > lo1) || !(mid1 < hi1))) done1 = true;
    if (done0) mid0 = lo0;
    if (done1) mid1 = lo1;
    if (done0 && done1) break;
    int c0 = 0, c1 = 0;
#pragma unroll
    for (int i = 0; i < VPT; ++i) {
      c0 += (int)__popcll(__ballot(za0[i] >= mid0));
      c1 += (int)__popcll(__ballot(za1[i] >= mid1));
    }
    if (!done0) {
      if (c0 >= TOPK) { lo0 = mid0; if (c0 == TOPK) done0 = true; }
      else hi0 = mid0;
    }
    if (!done1) {
      if (c1 >= TOPK) { lo1 = mid1; if (c1 == TOPK) done1 = true; }
      else hi1 = mid1;
    }
  }
  const float t0 = lo0, t1 = lo1;

  // top32_sum = sum(strictly greater) + ties at t filling to TOPK.
  float s0 = 0.0f, s1 = 0.0f;
  int cg0 = 0, cg1 = 0;
#pragma unroll
  for (int i = 0; i < VPT; ++i) {
    const bool b0 = za0[i] > t0;
    const bool b1 = za1[i] > t1;
    s0 += b0 ? za0[i] : 0.0f;
    s1 += b1 ? za1[i] : 0.0f;
    cg0 += (int)__popcll(__ballot(b0));
    cg1 += (int)__popcll(__ballot(b1));
  }
  waveSum2(s0, s1);
  const float ea = ws[D], es = ws[D + 1];
  const float surp0 = (s0 + (float)(TOPK - cg0) * t0) * (1.0f / (float)TOPK);
  const float surp1 = (s1 + (float)(TOPK - cg1) * t1) * (1.0f / (float)TOPK);
  const float gate0 = 1.0f + ea * fast_tanh_pos(es * surp0);
  const float gate1 = 1.0f + ea * fast_tanh_pos(es * surp1);

  float* __restrict__ o0 = out + (size_t)row0 * D;
#pragma unroll
  for (int j = 0; j < 4; ++j) {
    const int c = j * 256 + lane * 4;
    vfloat4 o;
    o.x = g0[4 * j + 0] * gate0;
    o.y = g0[4 * j + 1] * gate0;
    o.z = g0[4 * j + 2] * gate0;
    o.w = g0[4 * j + 3] * gate0;
    __builtin_nontemporal_store(o, reinterpret_cast<vfloat4*>(o0 + c));
  }
  if (has1) {
    float* __restrict__ o1 = out + (size_t)(row0 + 1) * D;
#pragma unroll
    for (int j = 0; j < 4; ++j) {
      const int c = j * 256 + lane * 4;
      vfloat4 o;
      o.x = g1[4 * j + 0] * gate1;
      o.y = g1[4 * j + 1] * gate1;
      o.z = g1[4 * j + 2] * gate1;
      o.w = g1[4 * j + 3] * gate1;
      __builtin_nontemporal_store(o, reinterpret_cast<vfloat4*>(o1 + c));
    }
  }
}

extern "C" void kernel_launch(void* const* d_in, const int* in_sizes, int n_in,
                              void* d_out, int out_size, void* d_ws, size_t ws_size,
                              hipStream_t stream) {
  const float* x    = (const float*)d_in[0];
  const float* la   = (const float*)d_in[1];
  const float* ls   = (const float*)d_in[2];
  const float* mean = (const float*)d_in[3];
  const float* sq   = (const float*)d_in[4];
  float* out = (float*)d_out;
  float* ws = (float*)d_ws;  // [0..D): inv_std, [D]: e^la, [D+1]: e^ls

  const int n = in_sizes[0];
  const int n_rows = n / D;

  prep_stats<<<(D + 255) / 256, 256, 0, stream>>>(mean, sq, la, ls, ws);

  const int rows_per_block = RPW * WAVES;
  const int grid = (n_rows + rows_per_block - 1) / rows_per_block;
  gelu_gate<<<grid, WAVES * 64, 0, stream>>>(x, mean, ws, out, n_rows);
}